// Round 1
// baseline (694.614 us; speedup 1.0000x reference)
//
#include <hip/hip_runtime.h>
#include <math.h>

#define Bn 128
#define Tn 16
#define TOn 32
#define Jn 25
#define INn 256
#define OUTn 512
#define Hn 8
#define NEGC (-1000000000.0f)

// ---------------------------------------------------------------------------
// Index algebra (derived from the reference's reshape of (B,TO,J,OUT) into
// (B,H,TO,J,hid)): element (b,h,p',j',c) lives at original row p = kmul*h + (p'>>3)
// (kmul = 4 for Q/TO, 2 for K,V/T), with g = 25*(p'&7) + j', orig j = g>>3,
// orig feature o = 64*(g&7) + c.  hs = 32 (low half spatial, high half temporal).
//
// Simplifications used:
//  - q,k only needed as sums over c<32 of each 64-chunk  -> pre-reduced weights
//  - softmax(attn_t).sum(-1) == 1  -> x_t = sum_t' v_t (q_t,k_t,mask_t dead)
//  - V reduced per (b,t) to P[a,c] = sum_{g=25a..25a+24} Vflat[g,c]   (c<32)
//                        and U[jp,c] = sum_a Vflat[25a+jp, 32+c]      (c<32)
// ---------------------------------------------------------------------------

// ws layout (float offsets)
#define OFF_WQSUM 0          // 8*256
#define OFF_WKSUM 2048       // 8*256
#define OFF_BQSUM 4096       // 8
#define OFF_BKSUM 4104       // 8
#define OFF_WVT   4112       // 256*512
#define OFF_QLOW  135184     // B*TO*200
#define OFF_KLOW  954384     // B*T*200
#define OFF_P     1363984    // B*T*8*32
#define OFF_U     1888272    // B*T*25*32
#define OFF_VS    3526672    // B*H*TO*32
#define OFF_KS    4575248    // B*H*TO*25
// total 5394448 floats = 21.6 MB

__global__ void k_wsum(const float* __restrict__ Wq, const float* __restrict__ bq,
                       const float* __restrict__ Wk, const float* __restrict__ bk,
                       float* __restrict__ ws) {
    int mat = blockIdx.x >> 3, u = blockIdx.x & 7, k = threadIdx.x;
    const float* W  = mat ? Wk : Wq;
    const float* bb = mat ? bk : bq;
    float* wout = ws + (mat ? OFF_WKSUM : OFF_WQSUM);
    float* bout = ws + (mat ? OFF_BKSUM : OFF_BQSUM);
    float s = 0.f;
    for (int i = 0; i < 32; ++i) s += W[(u * 64 + i) * 256 + k];
    wout[u * 256 + k] = s;
    if (k == 0) {
        float sb = 0.f;
        for (int i = 0; i < 32; ++i) sb += bb[u * 64 + i];
        bout[u] = sb;
    }
}

__global__ void k_transpose(const float* __restrict__ Wv, float* __restrict__ WvT) {
    int idx = blockIdx.x * 256 + threadIdx.x;   // 131072 total
    int o = idx >> 8, k = idx & 255;
    WvT[k * 512 + o] = Wv[idx];
}

// rows of 256 floats -> 8 half-chunk sums per row: out[row*8+u] = X_row . wsum[u]
__global__ void k_lowsum(const float* __restrict__ X, const float* __restrict__ wsum,
                         const float* __restrict__ bsum, float* __restrict__ out,
                         int nrows) {
    int lane = threadIdx.x & 63;
    int wave = threadIdx.x >> 6;
    float4 w[8];
#pragma unroll
    for (int u = 0; u < 8; ++u) w[u] = *(const float4*)(wsum + u * 256 + lane * 4);
    float bs[8];
#pragma unroll
    for (int u = 0; u < 8; ++u) bs[u] = bsum[u];
    for (int row = blockIdx.x * 4 + wave; row < nrows; row += gridDim.x * 4) {
        float4 x = *(const float4*)(X + (size_t)row * 256 + lane * 4);
        float p[8];
#pragma unroll
        for (int u = 0; u < 8; ++u)
            p[u] = x.x * w[u].x + x.y * w[u].y + x.z * w[u].z + x.w * w[u].w;
#pragma unroll
        for (int m = 1; m < 64; m <<= 1) {
#pragma unroll
            for (int u = 0; u < 8; ++u) p[u] += __shfl_xor(p[u], m, 64);
        }
        if (lane == 0) {
#pragma unroll
            for (int u = 0; u < 8; ++u) out[(size_t)row * 8 + u] = p[u] + bs[u];
        }
    }
}

// per (b,t): V(25x512) = enc(25x256) @ Wv^T, reduced in-LDS to P[8][32], U[25][32]
__global__ __launch_bounds__(256) void k_vgemm(const float* __restrict__ enc,
                                               const float* __restrict__ WvT,
                                               const float* __restrict__ bv,
                                               float* __restrict__ P,
                                               float* __restrict__ U) {
    __shared__ float smem[12800];   // first used as enc (25*256), then as V (25*512)
    int bt = blockIdx.x;            // b*16 + t
    int tid = threadIdx.x;          // 256
    for (int s = tid; s < 6400; s += 256) smem[s] = enc[(size_t)bt * 6400 + s];
    __syncthreads();
    float bvr0 = bv[tid], bvr1 = bv[tid + 256];
    float acc[25][2];
#pragma unroll
    for (int j = 0; j < 25; ++j) { acc[j][0] = 0.f; acc[j][1] = 0.f; }
    for (int k0 = 0; k0 < 256; k0 += 4) {
        float wv[4][2];
#pragma unroll
        for (int kk = 0; kk < 4; ++kk) {
            wv[kk][0] = WvT[(k0 + kk) * 512 + tid];
            wv[kk][1] = WvT[(k0 + kk) * 512 + tid + 256];
        }
#pragma unroll
        for (int j = 0; j < 25; ++j) {
            float4 e = *(const float4*)&smem[j * 256 + k0];
            acc[j][0] += e.x * wv[0][0] + e.y * wv[1][0] + e.z * wv[2][0] + e.w * wv[3][0];
            acc[j][1] += e.x * wv[0][1] + e.y * wv[1][1] + e.z * wv[2][1] + e.w * wv[3][1];
        }
    }
    __syncthreads();
#pragma unroll
    for (int j = 0; j < 25; ++j) {
        smem[j * 512 + tid]       = acc[j][0] + bvr0;
        smem[j * 512 + tid + 256] = acc[j][1] + bvr1;
    }
    __syncthreads();
    {   // P: 256 slots, one per thread
        int a = tid >> 5, c = tid & 31;
        float sum = 0.f;
        for (int g = 25 * a; g < 25 * a + 25; ++g)
            sum += smem[(g >> 3) * 512 + ((g & 7) << 6) + c];
        P[(size_t)bt * 256 + tid] = sum;
    }
    for (int s = tid; s < 800; s += 256) {   // U: 800 slots
        int jp = s >> 5, c = s & 31;
        float sum = 0.f;
#pragma unroll
        for (int a = 0; a < 8; ++a) {
            int g = 25 * a + jp;
            sum += smem[(g >> 3) * 512 + ((g & 7) << 6) + 32 + c];
        }
        U[(size_t)bt * 800 + s] = sum;
    }
}

// per (b,h): vs_sum[to][c] and ks_sum[to][j] via Wconv contraction over t'
__global__ void k_convsum(const float* __restrict__ P, const float* __restrict__ klow,
                          const float* __restrict__ Wconv, const float* __restrict__ bconv,
                          float* __restrict__ vssum, float* __restrict__ kssum) {
    __shared__ float Pl[512], kl[400], Wc[512], bc[32];
    int bh = blockIdx.x;            // b*8 + h
    int b = bh >> 3, h = bh & 7;
    int tid = threadIdx.x;          // 256
    int base = b * 16 + 2 * h;
    for (int s = tid; s < 512; s += 256) { Pl[s] = P[(size_t)base * 256 + s]; Wc[s] = Wconv[s]; }
    for (int s = tid; s < 400; s += 256) kl[s] = klow[(size_t)base * 200 + s];
    if (tid < 32) bc[tid] = bconv[tid];
    __syncthreads();
    for (int idx = tid; idx < 1024; idx += 256) {
        int to = idx >> 5, c = idx & 31;
        float s = 25.f * bc[to];
#pragma unroll
        for (int tp = 0; tp < 16; ++tp)
            s += Wc[to * 16 + tp] * Pl[(tp >> 3) * 256 + (tp & 7) * 32 + c];
        vssum[((size_t)bh * 32 + to) * 32 + c] = s;
    }
    for (int idx = tid; idx < 800; idx += 256) {
        int to = idx / 25, j = idx % 25;
        float s = 32.f * bc[to];
#pragma unroll
        for (int tp = 0; tp < 16; ++tp)
            s += Wc[to * 16 + tp] * kl[(tp >> 3) * 200 + 25 * (tp & 7) + j];
        kssum[((size_t)bh * 32 + to) * 25 + j] = s;
    }
}

// per (b,to'): masked rank-1 softmax diagonal + output assembly
__global__ void k_final(const float* __restrict__ qlow, const float* __restrict__ kssum,
                        const float* __restrict__ vssum, const float* __restrict__ U,
                        const int* __restrict__ mask_s, float* __restrict__ out) {
    __shared__ float qv[200], kv[200], vsl[256], dg[200], vt[6400];
    __shared__ int msk[625];
    int blk = blockIdx.x;           // b*32 + top
    int b = blk >> 5, top = blk & 31;
    int tid = threadIdx.x;          // 256
    for (int s = tid; s < 625; s += 256) msk[s] = mask_s[top * 625 + s];
    if (tid < 200) {
        int h = tid / 25, i = tid % 25;
        qv[tid] = qlow[((size_t)b * 32 + 4 * h + (top >> 3)) * 200 + 25 * (top & 7) + i];
        kv[tid] = kssum[(((size_t)b * 8 + h) * 32 + top) * 25 + i];
    }
    {
        int h = tid >> 5, c = tid & 31;
        vsl[tid] = vssum[(((size_t)b * 8 + h) * 32 + top) * 32 + c];
    }
#pragma unroll
    for (int h = 0; h < 8; ++h) {
        for (int s = tid; s < 800; s += 256)
            vt[h * 800 + s] = U[((size_t)b * 16 + 2 * h) * 800 + s]
                            + U[((size_t)b * 16 + 2 * h + 1) * 800 + s];
    }
    __syncthreads();
    if (tid < 200) {
        int h = tid / 25, i = tid % 25;
        float q = qv[tid];
        float m = -3.0e38f;
#pragma unroll
        for (int j = 0; j < 25; ++j) {
            float a = msk[i * 25 + j] ? q * kv[h * 25 + j] : NEGC;
            m = fmaxf(m, a);
        }
        float sum = 0.f;
#pragma unroll
        for (int j = 0; j < 25; ++j) {
            float a = msk[i * 25 + j] ? q * kv[h * 25 + j] : NEGC;
            sum += expf(a - m);
        }
        float ai = msk[i * 25 + i] ? q * kv[h * 25 + i] : NEGC;
        dg[tid] = expf(ai - m) / sum;
    }
    __syncthreads();
    float* outp = out + (size_t)blk * (25 * 512);
#pragma unroll 1
    for (int i = 0; i < 25; ++i) {
#pragma unroll
        for (int r = 0; r < 2; ++r) {
            int o = tid + 256 * r;
            int h = o >> 6, c = o & 63;
            float v = (c < 32) ? dg[h * 25 + i] * vsl[h * 32 + c]
                               : vt[(h * 25 + i) * 32 + (c - 32)];
            outp[i * 512 + o] = v;
        }
    }
}

extern "C" void kernel_launch(void* const* d_in, const int* in_sizes, int n_in,
                              void* d_out, int out_size, void* d_ws, size_t ws_size,
                              hipStream_t stream) {
    const float* x      = (const float*)d_in[0];
    const float* enc    = (const float*)d_in[1];
    const int*   mask_s = (const int*)d_in[2];
    // d_in[3] = mask_t: dead (softmax(attn_t).sum(-1) == 1)
    const float* Wq     = (const float*)d_in[4];
    const float* bq     = (const float*)d_in[5];
    const float* Wk     = (const float*)d_in[6];
    const float* bk     = (const float*)d_in[7];
    const float* Wv     = (const float*)d_in[8];
    const float* bv     = (const float*)d_in[9];
    const float* Wconv  = (const float*)d_in[10];
    const float* bconv  = (const float*)d_in[11];
    float* out = (float*)d_out;
    float* ws  = (float*)d_ws;

    float* wqsum = ws + OFF_WQSUM;
    float* wksum = ws + OFF_WKSUM;
    float* bqsum = ws + OFF_BQSUM;
    float* bksum = ws + OFF_BKSUM;
    float* WvT   = ws + OFF_WVT;
    float* qlow  = ws + OFF_QLOW;
    float* klow  = ws + OFF_KLOW;
    float* Pbuf  = ws + OFF_P;
    float* Ubuf  = ws + OFF_U;
    float* vssum = ws + OFF_VS;
    float* kssum = ws + OFF_KS;

    hipLaunchKernelGGL(k_wsum, dim3(16), dim3(256), 0, stream, Wq, bq, Wk, bk, ws);
    hipLaunchKernelGGL(k_transpose, dim3(512), dim3(256), 0, stream, Wv, WvT);
    hipLaunchKernelGGL(k_lowsum, dim3(2048), dim3(256), 0, stream,
                       x, wqsum, bqsum, qlow, Bn * TOn * Jn);
    hipLaunchKernelGGL(k_lowsum, dim3(1024), dim3(256), 0, stream,
                       enc, wksum, bksum, klow, Bn * Tn * Jn);
    hipLaunchKernelGGL(k_vgemm, dim3(Bn * Tn), dim3(256), 0, stream,
                       enc, WvT, bv, Pbuf, Ubuf);
    hipLaunchKernelGGL(k_convsum, dim3(Bn * Hn), dim3(256), 0, stream,
                       Pbuf, klow, Wconv, bconv, vssum, kssum);
    hipLaunchKernelGGL(k_final, dim3(Bn * TOn), dim3(256), 0, stream,
                       qlow, kssum, vssum, Ubuf, mask_s, out);
}

// Round 3
// 489.616 us; speedup vs baseline: 1.4187x; 1.4187x over previous
//
#include <hip/hip_runtime.h>
#include <math.h>

#define Bn 128
#define Tn 16
#define TOn 32
#define Jn 25
#define INn 256
#define OUTn 512
#define Hn 8
#define NEGC (-1000000000.0f)

// ---------------------------------------------------------------------------
// Index algebra (see R1 notes): reshape (B,TO,J,OUT)->(B,H,TO,J,hid) maps
// (h,p',j',c) -> orig row p = kmul*h + (p'>>3), g = 25*(p'&7)+j', j=g>>3,
// o = 64*(g&7)+c.  hs=32.  Simplifications:
//  - q,k only used as channel-sums -> pre-reduced weights (k_wsum/k_lowsum)
//  - softmax(attn_t).sum(-1)==1 -> x_t = sum_t v_t (q_t,k_t,mask_t dead)
//  - V reduced per (b,t) to P[8][32], U[25][32]; vt[b][h] = U[2h]+U[2h+1]
// R2: V-GEMM via bf16 MFMA 32x32x16; enc bf16 staged in d_out scratch.
// R3: fix vt batch stride in k_final (b*6400, was b*51200 -> OOB garbage).
// ---------------------------------------------------------------------------

// ws layout (float offsets)
#define OFF_WQSUM 0          // 2048
#define OFF_WKSUM 2048       // 2048
#define OFF_BQSUM 4096       // 8
#define OFF_BKSUM 4104       // 8
#define OFF_WVB   4112       // 131072 shorts = 65536 floats
#define OFF_QLOW  69648      // 128*32*200
#define OFF_KLOW  888848     // 128*16*200
#define OFF_P     1298448    // 128*16*256
#define OFF_U     1822736    // 128*16*800
#define OFF_VT    3461136    // 128*8*800
#define OFF_VS    4280336    // 128*8*32*32
#define OFF_KS    5328912    // 128*8*32*25
// total 6148112 floats = 24.6 MB

typedef __attribute__((ext_vector_type(8))) short s16x8;
typedef __attribute__((ext_vector_type(16))) float f32x16;

__device__ inline short f2bf(float f) {
    union { float f; unsigned u; } v; v.f = f;
    unsigned r = v.u + 0x7fffu + ((v.u >> 16) & 1u);
    return (short)(r >> 16);
}

__global__ void k_wsum(const float* __restrict__ Wq, const float* __restrict__ bq,
                       const float* __restrict__ Wk, const float* __restrict__ bk,
                       float* __restrict__ ws) {
    int mat = blockIdx.x >> 3, u = blockIdx.x & 7, k = threadIdx.x;
    const float* W  = mat ? Wk : Wq;
    const float* bb = mat ? bk : bq;
    float* wout = ws + (mat ? OFF_WKSUM : OFF_WQSUM);
    float* bout = ws + (mat ? OFF_BKSUM : OFF_BQSUM);
    float s = 0.f;
    for (int i = 0; i < 32; ++i) s += W[(u * 64 + i) * 256 + k];
    wout[u * 256 + k] = s;
    if (k == 0) {
        float sb = 0.f;
        for (int i = 0; i < 32; ++i) sb += bb[u * 64 + i];
        bout[u] = sb;
    }
}

__global__ void k_wvbf16(const float* __restrict__ Wv, short* __restrict__ Wvb) {
    int idx = blockIdx.x * 256 + threadIdx.x;   // 131072
    Wvb[idx] = f2bf(Wv[idx]);
}

// rows of 256 floats -> 8 half-chunk sums per row; optionally emit bf16 rows
__global__ void k_lowsum(const float* __restrict__ X, const float* __restrict__ wsum,
                         const float* __restrict__ bsum, float* __restrict__ out,
                         short* __restrict__ encb, int nrows) {
    int lane = threadIdx.x & 63;
    int wave = threadIdx.x >> 6;
    float4 w[8];
#pragma unroll
    for (int u = 0; u < 8; ++u) w[u] = *(const float4*)(wsum + u * 256 + lane * 4);
    float bs[8];
#pragma unroll
    for (int u = 0; u < 8; ++u) bs[u] = bsum[u];
    for (int row = blockIdx.x * 4 + wave; row < nrows; row += gridDim.x * 4) {
        float4 x = *(const float4*)(X + (size_t)row * 256 + lane * 4);
        if (encb) {
            short4 sv;
            sv.x = f2bf(x.x); sv.y = f2bf(x.y); sv.z = f2bf(x.z); sv.w = f2bf(x.w);
            *(short4*)(encb + (size_t)row * 256 + lane * 4) = sv;
        }
        float p[8];
#pragma unroll
        for (int u = 0; u < 8; ++u)
            p[u] = x.x * w[u].x + x.y * w[u].y + x.z * w[u].z + x.w * w[u].w;
#pragma unroll
        for (int m = 1; m < 64; m <<= 1) {
#pragma unroll
            for (int u = 0; u < 8; ++u) p[u] += __shfl_xor(p[u], m, 64);
        }
        if (lane == 0) {
#pragma unroll
            for (int u = 0; u < 8; ++u) out[(size_t)row * 8 + u] = p[u] + bs[u];
        }
    }
}

// per (b,t): V(25x512) = enc(25x256) @ Wv^T via bf16 MFMA, reduced to P, U
__global__ __launch_bounds__(256) void k_vgemm(const short* __restrict__ encb,
                                               const short* __restrict__ Wvb,
                                               const float* __restrict__ bv,
                                               float* __restrict__ P,
                                               float* __restrict__ U) {
    __shared__ float Vs[25 * 520];   // 52 KB, stride 520 kills bank conflicts
    int bt = blockIdx.x;             // b*16 + t
    int tid = threadIdx.x, lane = tid & 63, wave = tid >> 6;
    int m = lane & 31;               // A row / B col within tile
    int kq = (lane >> 5) * 8;        // k sub-offset (0 or 8)
    bool mok = (m < 25);
    const short* aptr = encb + (size_t)bt * 6400 + m * 256 + kq;
    int n0 = wave * 4;               // 4 n-tiles of 32 per wave
    const short* bptr[4];
#pragma unroll
    for (int t = 0; t < 4; ++t)
        bptr[t] = Wvb + ((n0 + t) * 32 + m) * 256 + kq;

    f32x16 acc[4];
#pragma unroll
    for (int t = 0; t < 4; ++t)
#pragma unroll
        for (int r = 0; r < 16; ++r) acc[t][r] = 0.f;

    const s16x8 za = (s16x8)(short)0;
#pragma unroll 4
    for (int ks = 0; ks < 16; ++ks) {
        s16x8 afrag = za;
        if (mok) afrag = *(const s16x8*)(aptr + ks * 16);
#pragma unroll
        for (int t = 0; t < 4; ++t) {
            s16x8 bfrag = *(const s16x8*)(bptr[t] + ks * 16);
            acc[t] = __builtin_amdgcn_mfma_f32_32x32x16_bf16(afrag, bfrag, acc[t], 0, 0, 0);
        }
    }

    // C/D layout: col = lane&31, row = (reg&3) + 8*(reg>>2) + 4*(lane>>5)
    int rbase = 4 * (lane >> 5);
#pragma unroll
    for (int t = 0; t < 4; ++t) {
        int col = (n0 + t) * 32 + (lane & 31);
        float bvv = bv[col];
#pragma unroll
        for (int r = 0; r < 16; ++r) {
            int row = (r & 3) + 8 * (r >> 2) + rbase;
            if (row < 25) Vs[row * 520 + col] = acc[t][r] + bvv;
        }
    }
    __syncthreads();
    {   // P: 256 slots
        int a = tid >> 5, c = tid & 31;
        float sum = 0.f;
        for (int g = 25 * a; g < 25 * a + 25; ++g)
            sum += Vs[(g >> 3) * 520 + ((g & 7) << 6) + c];
        P[(size_t)bt * 256 + tid] = sum;
    }
    for (int s = tid; s < 800; s += 256) {   // U: 800 slots
        int jp = s >> 5, c = s & 31;
        float sum = 0.f;
#pragma unroll
        for (int a = 0; a < 8; ++a) {
            int g = 25 * a + jp;
            sum += Vs[(g >> 3) * 520 + ((g & 7) << 6) + 32 + c];
        }
        U[(size_t)bt * 800 + s] = sum;
    }
}

// vt[b*6400 + h*800 + s] = U[b*16+2h][s] + U[b*16+2h+1][s]
__global__ void k_vt(const float* __restrict__ U, float* __restrict__ vt) {
    int idx = blockIdx.x * 256 + threadIdx.x;   // 819200
    int b = idx / 6400, r = idx - b * 6400;
    int h = r / 800, s = r - h * 800;
    vt[idx] = U[((size_t)b * 16 + 2 * h) * 800 + s]
            + U[((size_t)b * 16 + 2 * h + 1) * 800 + s];
}

// per (b,h): vs_sum[to][c] and ks_sum[to][j] via Wconv contraction over t'
__global__ void k_convsum(const float* __restrict__ P, const float* __restrict__ klow,
                          const float* __restrict__ Wconv, const float* __restrict__ bconv,
                          float* __restrict__ vssum, float* __restrict__ kssum) {
    __shared__ float Pl[512], kl[400], Wc[512], bc[32];
    int bh = blockIdx.x;            // b*8 + h
    int b = bh >> 3, h = bh & 7;
    int tid = threadIdx.x;          // 256
    int base = b * 16 + 2 * h;
    for (int s = tid; s < 512; s += 256) { Pl[s] = P[(size_t)base * 256 + s]; Wc[s] = Wconv[s]; }
    for (int s = tid; s < 400; s += 256) kl[s] = klow[(size_t)base * 200 + s];
    if (tid < 32) bc[tid] = bconv[tid];
    __syncthreads();
    for (int idx = tid; idx < 1024; idx += 256) {
        int to = idx >> 5, c = idx & 31;
        float s = 25.f * bc[to];
#pragma unroll
        for (int tp = 0; tp < 16; ++tp)
            s += Wc[to * 16 + tp] * Pl[(tp >> 3) * 256 + (tp & 7) * 32 + c];
        vssum[((size_t)bh * 32 + to) * 32 + c] = s;
    }
    for (int idx = tid; idx < 800; idx += 256) {
        int to = idx / 25, j = idx - 25 * (idx / 25);
        float s = 32.f * bc[to];
#pragma unroll
        for (int tp = 0; tp < 16; ++tp)
            s += Wc[to * 16 + tp] * kl[(tp >> 3) * 200 + 25 * (tp & 7) + j];
        kssum[((size_t)bh * 32 + to) * 25 + j] = s;
    }
}

// per (b,to'): masked rank-1 softmax diagonal + float4 output assembly
__global__ __launch_bounds__(256) void k_final(const float* __restrict__ qlow,
                        const float* __restrict__ kssum,
                        const float* __restrict__ vssum, const float* __restrict__ vt,
                        const int* __restrict__ mask_s, float* __restrict__ out) {
    __shared__ float qv[200], kv[200], vsl[8 * 36], dg[200];
    __shared__ int msk[625];
    int blk = blockIdx.x;           // b*32 + top
    int b = blk >> 5, top = blk & 31;
    int tid = threadIdx.x;          // 256
    for (int s = tid; s < 625; s += 256) msk[s] = mask_s[top * 625 + s];
    if (tid < 200) {
        int h = tid / 25, i = tid - 25 * (tid / 25);
        qv[tid] = qlow[((size_t)b * 32 + 4 * h + (top >> 3)) * 200 + 25 * (top & 7) + i];
        kv[tid] = kssum[(((size_t)b * 8 + h) * 32 + top) * 25 + i];
    }
    {
        int h = tid >> 5, c = tid & 31;
        vsl[h * 36 + c] = vssum[(((size_t)b * 8 + h) * 32 + top) * 32 + c];
    }
    __syncthreads();
    if (tid < 200) {
        int h = tid / 25, i = tid - 25 * (tid / 25);
        float q = qv[tid];
        float m = -3.0e38f;
#pragma unroll
        for (int j = 0; j < 25; ++j) {
            float a = msk[i * 25 + j] ? q * kv[h * 25 + j] : NEGC;
            m = fmaxf(m, a);
        }
        float sum = 0.f;
#pragma unroll
        for (int j = 0; j < 25; ++j) {
            float a = msk[i * 25 + j] ? q * kv[h * 25 + j] : NEGC;
            sum += expf(a - m);
        }
        float ai = msk[i * 25 + i] ? q * kv[h * 25 + i] : NEGC;
        dg[tid] = expf(ai - m) / sum;
    }
    __syncthreads();
    float4* outp = (float4*)(out + (size_t)blk * 12800);
    const float4* vtb = (const float4*)(vt + (size_t)b * 6400);
#pragma unroll 1
    for (int q = tid; q < 3200; q += 256) {   // q = i*128 + o4
        int i = q >> 7, o4 = q & 127, h = o4 >> 4, e = o4 & 15;
        float4 r;
        if (e < 8) {            // spatial half: c = 4e
            float d = dg[h * 25 + i];
            const float* vp = &vsl[h * 36 + 4 * e];
            r.x = d * vp[0]; r.y = d * vp[1]; r.z = d * vp[2]; r.w = d * vp[3];
        } else {                // temporal half: c-32 = 4(e-8)
            r = vtb[(h * 25 + i) * 8 + (e - 8)];
        }
        outp[q] = r;
    }
}

extern "C" void kernel_launch(void* const* d_in, const int* in_sizes, int n_in,
                              void* d_out, int out_size, void* d_ws, size_t ws_size,
                              hipStream_t stream) {
    const float* x      = (const float*)d_in[0];
    const float* enc    = (const float*)d_in[1];
    const int*   mask_s = (const int*)d_in[2];
    // d_in[3] = mask_t: dead
    const float* Wq     = (const float*)d_in[4];
    const float* bq     = (const float*)d_in[5];
    const float* Wk     = (const float*)d_in[6];
    const float* bk     = (const float*)d_in[7];
    const float* Wv     = (const float*)d_in[8];
    const float* bv     = (const float*)d_in[9];
    const float* Wconv  = (const float*)d_in[10];
    const float* bconv  = (const float*)d_in[11];
    float* out = (float*)d_out;
    float* ws  = (float*)d_ws;

    float* wqsum = ws + OFF_WQSUM;
    float* wksum = ws + OFF_WKSUM;
    float* bqsum = ws + OFF_BQSUM;
    float* bksum = ws + OFF_BKSUM;
    short* Wvb   = (short*)(ws + OFF_WVB);
    float* qlow  = ws + OFF_QLOW;
    float* klow  = ws + OFF_KLOW;
    float* Pbuf  = ws + OFF_P;
    float* Ubuf  = ws + OFF_U;
    float* vtbuf = ws + OFF_VT;
    float* vssum = ws + OFF_VS;
    float* kssum = ws + OFF_KS;
    // enc in bf16 staged in d_out (209 MB, fully overwritten by k_final later)
    short* encb  = (short*)d_out;

    hipLaunchKernelGGL(k_wsum, dim3(16), dim3(256), 0, stream, Wq, bq, Wk, bk, ws);
    hipLaunchKernelGGL(k_wvbf16, dim3(512), dim3(256), 0, stream, Wv, Wvb);
    hipLaunchKernelGGL(k_lowsum, dim3(2048), dim3(256), 0, stream,
                       x, wqsum, bqsum, qlow, (short*)nullptr, Bn * TOn * Jn);
    hipLaunchKernelGGL(k_lowsum, dim3(1024), dim3(256), 0, stream,
                       enc, wksum, bksum, klow, encb, Bn * Tn * Jn);
    hipLaunchKernelGGL(k_vgemm, dim3(Bn * Tn), dim3(256), 0, stream,
                       encb, Wvb, bv, Pbuf, Ubuf);
    hipLaunchKernelGGL(k_vt, dim3(3200), dim3(256), 0, stream, Ubuf, vtbuf);
    hipLaunchKernelGGL(k_convsum, dim3(Bn * Hn), dim3(256), 0, stream,
                       Pbuf, klow, Wconv, bconv, vssum, kssum);
    hipLaunchKernelGGL(k_final, dim3(Bn * TOn), dim3(256), 0, stream,
                       qlow, kssum, vssum, vtbuf, mask_s, out);
}